// Round 7
// baseline (162.432 us; speedup 1.0000x reference)
//
#include <hip/hip_runtime.h>
#include <math.h>

#define N_MELS   128
#define N_FFT    2048
#define HOP      512
#define BATCH    8
#define S_LEN    661500
#define CH       2
#define T_FRAMES 1292            // 1 + S_LEN/HOP
#define NBINS    1025            // 1 + N_FFT/2

#define ANG 0.003067961575771282f   // 2*pi/2048

// d_ws layout (byte offsets)
#define WS_WIN     0        // float[2048]   hann window
#define WS_TW      8192     // float2[2048]  W_2048^j
#define WS_RANGES  24576    // int[256]      per-mel [start,end)

__device__ __forceinline__ float2 cadd(float2 a, float2 b){ return make_float2(a.x+b.x, a.y+b.y); }
__device__ __forceinline__ float2 csub(float2 a, float2 b){ return make_float2(a.x-b.x, a.y-b.y); }
__device__ __forceinline__ float2 cmul(float2 a, float2 b){ return make_float2(a.x*b.x - a.y*b.y, a.x*b.y + a.y*b.x); }
__device__ __forceinline__ float2 cnegi(float2 z){ return make_float2(z.y, -z.x); }   // -i*z

// Half-buffer padded layout: element e (in [0,1024)) lives at Z[e + 2*(e>>4)].
// Pad-2 per 16 keeps strided accesses quarter-wave conflict-free AND keeps
// stage-1's contiguous 8-runs 16B-aligned (base 8t+2*(t>>1) is always even).
#define ZPAD 1152            // 1024 + 2*64 float2 = 9216 B

// radix-8 DIF butterfly: b[k] = sum_j a[j] * W8^{jk}, W8 = exp(-i*pi/4)
__device__ __forceinline__ void bfly8(const float2* a, float2* b) {
    const float C = 0.70710678118654752f;
    float2 e0=cadd(a[0],a[4]), e1=cadd(a[1],a[5]), e2=cadd(a[2],a[6]), e3=cadd(a[3],a[7]);
    float2 o0=csub(a[0],a[4]), o1=csub(a[1],a[5]), o2=csub(a[2],a[6]), o3=csub(a[3],a[7]);
    float2 t1 = make_float2(C*(o1.x+o1.y), C*(o1.y-o1.x));      // o1*W8^1
    float2 t2 = make_float2(o2.y, -o2.x);                        // o2*W8^2 (-i)
    float2 t3 = make_float2(C*(o3.y-o3.x), -C*(o3.x+o3.y));      // o3*W8^3
    {
        float2 s0=cadd(e0,e2), d0=csub(e0,e2);
        float2 s1=cadd(e1,e3), d1=csub(e1,e3);
        b[0]=cadd(s0,s1); b[4]=csub(s0,s1);
        b[2]=cadd(d0,cnegi(d1)); b[6]=csub(d0,cnegi(d1));
    }
    {
        float2 s0=cadd(o0,t2), d0=csub(o0,t2);
        float2 s1=cadd(t1,t3), d1=csub(t1,t3);
        b[1]=cadd(s0,s1); b[5]=csub(s0,s1);
        b[3]=cadd(d0,cnegi(d1)); b[7]=csub(d0,cnegi(d1));
    }
}

// apply twiddle chain w1^k to bq[k] (k=1..7), result in w8
__device__ __forceinline__ void twiddle8(const float2* bq, float2 w1, float2* w8) {
    w8[0] = bq[0];
    float2 wk = w1;
    #pragma unroll
    for (int k = 1; k < 8; ++k) { w8[k] = cmul(wk, bq[k]); wk = cmul(wk, w1); }
}

// two-channel untangle: (|A|^2, |B|^2) for Zf, Zm = Z[N-f]
__device__ __forceinline__ float2 upair(float2 Zf, float2 Zm) {
    float br = Zm.x, bi = -Zm.y;
    float e0 = Zf.x + br, e1 = Zf.y + bi;
    float o0 = Zf.y - bi, o1 = Zf.x - br;
    return make_float2(0.25f*(e0*e0 + e1*e1), 0.25f*(o0*o0 + o1*o1));
}

// --- merged setup: blocks 0..7 build tables, blocks 8..135 scan one mel row each ---
__global__ __launch_bounds__(256) void setup_kernel(
        const float* __restrict__ fb, float* __restrict__ ws) {
    int blk = blockIdx.x;
    if (blk < 8) {
        int i = blk * 256 + threadIdx.x;
        float*  win = ws;
        float2* tw  = (float2*)((char*)ws + WS_TW);
        win[i] = 0.5f - 0.5f * cosf(ANG * (float)i);
        float sn, cs; sincosf(-ANG * (float)i, &sn, &cs);
        tw[i] = make_float2(cs, sn);
    } else {
        int m = blk - 8;
        int lane = threadIdx.x;
        if (lane < 64) {
            int* ranges = (int*)((char*)ws + WS_RANGES);
            const float* row = fb + m * NBINS;
            int s = NBINS, e = -1;
            for (int f = lane; f < NBINS; f += 64) {
                if (row[f] != 0.0f) { if (f < s) s = f; if (f > e) e = f; }
            }
            #pragma unroll
            for (int o = 32; o; o >>= 1) {
                s = min(s, __shfl_xor(s, o));
                e = max(e, __shfl_xor(e, o));
            }
            if (lane == 0) {
                ranges[2*m]   = (e < 0) ? 0 : s;
                ranges[2*m+1] = e + 1;
            }
        }
    }
}

// --- main: register radix-8 FFT (2048 = 8*8*8*4), half-buffer exchanges ---
__global__ __launch_bounds__(256, 8) void mel_spec_kernel(
        const float* __restrict__ x, const float* __restrict__ fb,
        const float* __restrict__ ws, float* __restrict__ out) {
    __shared__ float4 Zq[ZPAD/2];            // 9216 B total
    float2* Z   = (float2*)Zq;
    float2* pw2 = (float2*)Zq;               // pw2[f] = (ch0,ch1), f in [0,1024]

    const float*  win    = ws;
    const float2* tw     = (const float2*)((const char*)ws + WS_TW);
    const int*    ranges = (const int*)((const char*)ws + WS_RANGES);

    const int tid = threadIdx.x;
    const int bid = blockIdx.x;
    const int b   = bid & 7;          // XCD-contiguous: one batch item per XCD
    const int t   = bid >> 3;

    const float2* xb = (const float2*)x + (size_t)b * S_LEN;
    const int tb = t*HOP - (N_FFT/2);

    float2 r[8], bq[8], w8[8];
    const int rb = tid + 2*(tid>>4);   // OFF(tid): read base, stride 288 per k

    // ---- Input: r[k] = z[tid + 256k] windowed (coalesced global loads).
    #pragma unroll
    for (int k = 0; k < 8; ++k) {
        int n  = tid + 256*k;
        int s0 = tb + n;
        if (s0 < 0) s0 = -s0; else if (s0 >= S_LEN) s0 = 2*S_LEN - 2 - s0;
        float2 v = xb[s0];
        float  w = win[n];
        r[k] = make_float2(v.x*w, v.y*w);
    }

    // ======== Stage 1: radix-8, s=1. Outputs e = 8*tid + k (contiguous -> b128).
    bfly8(r, bq);
    twiddle8(bq, tw[tid], w8);
    {
        if (tid < 128) {
            int f4 = 4*tid + (tid>>1);
            #pragma unroll
            for (int j = 0; j < 4; ++j)
                Zq[f4+j] = make_float4(w8[2*j].x, w8[2*j].y, w8[2*j+1].x, w8[2*j+1].y);
        }
        __syncthreads();
        r[0]=Z[rb]; r[1]=Z[rb+288]; r[2]=Z[rb+576]; r[3]=Z[rb+864];
        __syncthreads();
        if (tid >= 128) {
            int tt = tid - 128;
            int f4 = 4*tt + (tt>>1);
            #pragma unroll
            for (int j = 0; j < 4; ++j)
                Zq[f4+j] = make_float4(w8[2*j].x, w8[2*j].y, w8[2*j+1].x, w8[2*j+1].y);
        }
        __syncthreads();
        r[4]=Z[rb]; r[5]=Z[rb+288]; r[6]=Z[rb+576]; r[7]=Z[rb+864];
        __syncthreads();
    }

    // ======== Stage 2: radix-8, s=8. Outputs e = q + 64a + 8k (q=tid&7, a=tid>>3).
    bfly8(r, bq);
    twiddle8(bq, tw[tid & ~7], w8);
    {
        int q = tid & 7, a = tid >> 3;
        if (tid < 128) {
            int base = q + 72*a;
            #pragma unroll
            for (int k = 0; k < 8; ++k) Z[base + 8*k + 2*(k>>1)] = w8[k];
        }
        __syncthreads();
        r[0]=Z[rb]; r[1]=Z[rb+288]; r[2]=Z[rb+576]; r[3]=Z[rb+864];
        __syncthreads();
        if (tid >= 128) {
            int base = q + 72*(a-16);
            #pragma unroll
            for (int k = 0; k < 8; ++k) Z[base + 8*k + 2*(k>>1)] = w8[k];
        }
        __syncthreads();
        r[4]=Z[rb]; r[5]=Z[rb+288]; r[6]=Z[rb+576]; r[7]=Z[rb+864];
        __syncthreads();
    }

    // ======== Stage 3: radix-8, s=64. Outputs e = q + 512a + 64k (q=tid&63, a=tid>>6).
    bfly8(r, bq);
    twiddle8(bq, tw[tid & ~63], w8);
    // Stage-4 butterfly pair: b1 = tid, b2 = 512-tid (tid=0 -> {0,256}).
    const int b1 = tid;
    const int b2 = (tid == 0) ? 256 : 512 - tid;
    const int rb1 = b1 + 2*(b1>>4);   // OFF(b1);  OFF(b1+512) = rb1+576
    const int rb2 = b2 + 2*(b2>>4);
    float2 A1[4], A2[4];
    {
        int q = tid & 63, a = tid >> 6;
        int qo = q + 2*(q>>4);
        if (tid < 128) {
            int base = qo + 576*a;                 // a in {0,1}
            #pragma unroll
            for (int k = 0; k < 8; ++k) Z[base + 72*k] = w8[k];
        }
        __syncthreads();
        A1[0]=Z[rb1]; A1[1]=Z[rb1+576]; A2[0]=Z[rb2]; A2[1]=Z[rb2+576];
        __syncthreads();
        if (tid >= 128) {
            int base = qo + 576*(a-2);             // a in {2,3}
            #pragma unroll
            for (int k = 0; k < 8; ++k) Z[base + 72*k] = w8[k];
        }
        __syncthreads();
        A1[2]=Z[rb1]; A1[3]=Z[rb1+576]; A2[2]=Z[rb2]; A2[3]=Z[rb2+576];
        __syncthreads();
    }

    // ======== Stage 4 (radix-4, s=512, twiddle-free) in registers.
    float2 O1[4], O2[4];
    {
        float2 apc=cadd(A1[0],A1[2]), amc=csub(A1[0],A1[2]);
        float2 bpd=cadd(A1[1],A1[3]), bmd=csub(A1[1],A1[3]);
        O1[0]=cadd(apc,bpd); O1[1]=cadd(amc,cnegi(bmd));
        O1[2]=csub(apc,bpd); O1[3]=csub(amc,cnegi(bmd));
    }
    {
        float2 apc=cadd(A2[0],A2[2]), amc=csub(A2[0],A2[2]);
        float2 bpd=cadd(A2[1],A2[3]), bmd=csub(A2[1],A2[3]);
        O2[0]=cadd(apc,bpd); O2[1]=cadd(amc,cnegi(bmd));
        O2[2]=csub(apc,bpd); O2[3]=csub(amc,cnegi(bmd));
    }

    // ======== Untangle in registers -> pw2 (aliases Z; all reads fenced above).
    if (tid == 0) {
        pw2[0]    = upair(O1[0], O1[0]);
        pw2[512]  = upair(O1[1], O1[3]);
        pw2[1024] = upair(O1[2], O1[2]);
        pw2[256]  = upair(O2[0], O2[3]);
        pw2[768]  = upair(O2[1], O2[2]);
    } else {
        pw2[tid]        = upair(O1[0], O2[3]);   // f = tid,      mate 2048-tid
        pw2[tid+512]    = upair(O1[1], O2[2]);   // f = tid+512,  mate 1536-tid
        pw2[512-tid]    = upair(O2[0], O1[3]);   // f = 512-tid,  mate 1536+tid
        pw2[1024-tid]   = upair(O2[1], O1[2]);   // f = 1024-tid, mate 1024+tid
    }
    __syncthreads();

    // ======== Sparse mel projection: (m,c) = (tid>>1, tid&1).
    {
        int m = tid >> 1;
        int c = tid & 1;
        int s0 = ranges[2*m];
        int e0 = ranges[2*m+1];
        const float* row = fb + m * NBINS;
        const float* pwf = (const float*)pw2;
        float acc = 0.0f;
        for (int f = s0; f < e0; ++f) acc += row[f] * pwf[2*f + c];
        out[(((size_t)b * N_MELS + m) * T_FRAMES + t) * CH + c] = acc;
    }
}

extern "C" void kernel_launch(void* const* d_in, const int* in_sizes, int n_in,
                              void* d_out, int out_size, void* d_ws, size_t ws_size,
                              hipStream_t stream) {
    const float* x  = (const float*)d_in[0];
    const float* fb = (const float*)d_in[1];
    float* out = (float*)d_out;
    float* ws  = (float*)d_ws;

    setup_kernel<<<8 + N_MELS, 256, 0, stream>>>(fb, ws);
    mel_spec_kernel<<<BATCH * T_FRAMES, 256, 0, stream>>>(x, fb, ws, out);
}